// Round 8
// baseline (90.617 us; speedup 1.0000x reference)
//
#include <hip/hip_runtime.h>
#include <hip/hip_bf16.h>
#include <type_traits>
#include <utility>

// Fused 2-layer Elman RNN + FC, round 8: R7 (M=32/block) with epilogue fix.
// B=16384, T=28, IN=28, H1=128, H2=64, NC=10.
// 512 blocks x 256 thr; block owns 32 batch rows (2 M-tiles per wave);
// waves N-split-4; 2 barriers/step; prepass bf16 weights in d_ws; native
// __bf16 casts. R7 bug: epilogue wrote 320 outputs with `if(tid<320)` over
// 256 threads -> rows 25..31/block never stored. Now a strided loop.

#define NBLK 512
#define NTHR 256

typedef float  f32x4 __attribute__((ext_vector_type(4)));
typedef short  s16x8 __attribute__((ext_vector_type(8)));
typedef __bf16 b16x8 __attribute__((ext_vector_type(8)));

template <typename V, typename = void> struct mfma_ok : std::false_type {};
template <typename V>
struct mfma_ok<V, std::void_t<decltype(__builtin_amdgcn_mfma_f32_16x16x32_bf16(
    std::declval<V>(), std::declval<V>(), std::declval<f32x4>(), 0, 0, 0))>>
    : std::true_type {};
using frag_t = std::conditional_t<mfma_ok<b16x8>::value, b16x8, s16x8>;

__device__ __forceinline__ f32x4 MFMA(frag_t a, frag_t b, f32x4 c) {
  return __builtin_amdgcn_mfma_f32_16x16x32_bf16(a, b, c, 0, 0, 0);
}

__device__ __forceinline__ unsigned short f2bf_n(float f) {  // native cvt (RNE)
  __bf16 h = (__bf16)f;
  return __builtin_bit_cast(unsigned short, h);
}
__device__ __forceinline__ frag_t packx(float4 a, float4 b) {
  s16x8 r;
  r[0]=(short)f2bf_n(a.x); r[1]=(short)f2bf_n(a.y); r[2]=(short)f2bf_n(a.z); r[3]=(short)f2bf_n(a.w);
  r[4]=(short)f2bf_n(b.x); r[5]=(short)f2bf_n(b.y); r[6]=(short)f2bf_n(b.z); r[7]=(short)f2bf_n(b.w);
  return __builtin_bit_cast(frag_t, r);
}
__device__ __forceinline__ float tanh_fast(float v) {
  float e = __expf(2.0f * v);
  return 1.0f - 2.0f / (e + 1.0f);
}

// ---- bf16 weight cache layout in d_ws (u16 elements) ----
#define OFF_WIH1 0        // [128][32]  (K padded 28->32 with zeros)
#define OFF_WHH1 4096     // [128][128]
#define OFF_WIH2 20480    // [64][128]
#define OFF_WHH2 28672    // [64][64]
#define OFF_WFC  32768    // [10][1792]
#define WS_U16   50688

__global__ void cvt_weights(const float* __restrict__ wih1, const float* __restrict__ whh1,
                            const float* __restrict__ wih2, const float* __restrict__ whh2,
                            const float* __restrict__ wfc,  unsigned short* __restrict__ ws)
{
  int i = blockIdx.x * 256 + threadIdx.x;
  if (i < 4096) {                       // W_ih1 padded
    int r = i >> 5, c = i & 31;
    ws[OFF_WIH1 + i] = (c < 28) ? f2bf_n(wih1[r * 28 + c]) : (unsigned short)0;
    return;
  }
  i -= 4096;
  if (i < 16384) { ws[OFF_WHH1 + i] = f2bf_n(whh1[i]); return; }
  i -= 16384;
  if (i < 8192)  { ws[OFF_WIH2 + i] = f2bf_n(wih2[i]); return; }
  i -= 8192;
  if (i < 4096)  { ws[OFF_WHH2 + i] = f2bf_n(whh2[i]); return; }
  i -= 4096;
  if (i < 17920) { ws[OFF_WFC + i] = f2bf_n(wfc[i]); return; }
}

__global__ __launch_bounds__(NTHR, 2)
void rnn_mfma8(const float* __restrict__ x,
               const unsigned short* __restrict__ ws,
               const float* __restrict__ b_ih1, const float* __restrict__ b_hh1,
               const float* __restrict__ b_ih2, const float* __restrict__ b_hh2,
               const float* __restrict__ b_fc,
               float* __restrict__ out)
{
  // LDS: 17408 + 9216 + 4096 = 30,720 B
  __shared__ alignas(16) unsigned short h1s[2][32][136];
  __shared__ alignas(16) unsigned short h2s[2][32][72];
  __shared__ alignas(16) float red[2][32][16];

  const int tid  = threadIdx.x;
  const int wn   = tid >> 6;          // wave = N-split index 0..3
  const int lane = tid & 63;
  const int li   = lane & 15;         // A-row-in-tile / D-col
  const int g    = lane >> 4;         // 0..3 k-group / D-row-group
  const int blk  = blockIdx.x;
  // XOR-16 column swizzle: (row,col) stored at col ^ (((row>>3)&1)<<4)
  const int swr  = ((li >> 3) & 1) << 4;          // reads:  row = m*16+li
  const int swv  = ((g  >> 1) & 1) << 4;          // writes: row = m*16+g*4+r

  // ---- per-wave weight B-frags ----
  const int n1 = wn * 32 + li;        // (+nt*16)
  const int n2 = wn * 16 + li;
  frag_t wB1[4][2], wBi1[2], wBi2[4], wB2[2];
  #pragma unroll
  for (int kt = 0; kt < 4; ++kt)
    #pragma unroll
    for (int nt = 0; nt < 2; ++nt)
      wB1[kt][nt] = *(const frag_t*)(ws + OFF_WHH1 + (n1 + nt * 16) * 128 + kt * 32 + g * 8);
  #pragma unroll
  for (int nt = 0; nt < 2; ++nt)
    wBi1[nt] = *(const frag_t*)(ws + OFF_WIH1 + (n1 + nt * 16) * 32 + g * 8);
  #pragma unroll
  for (int kt = 0; kt < 4; ++kt)
    wBi2[kt] = *(const frag_t*)(ws + OFF_WIH2 + n2 * 128 + kt * 32 + g * 8);
  #pragma unroll
  for (int kt = 0; kt < 2; ++kt)
    wB2[kt] = *(const frag_t*)(ws + OFF_WHH2 + n2 * 64 + kt * 32 + g * 8);

  float b1v[2];
  b1v[0] = b_ih1[n1] + b_hh1[n1];
  b1v[1] = b_ih1[n1 + 16] + b_hh1[n1 + 16];
  const float b2v = b_ih2[n2] + b_hh2[n2];

  const float* xrow0 = x + (size_t)(blk * 32 + li) * 784 + g * 8;
  const float* xrow1 = x + (size_t)(blk * 32 + 16 + li) * 784 + g * 8;
  const int    cls   = (li < 10) ? li : 0;
  const unsigned short* wfp = ws + OFF_WFC + cls * 1792 + (wn & 1) * 32 + g * 8;

  f32x4 fca[2] = {{0.f, 0.f, 0.f, 0.f}, {0.f, 0.f, 0.f, 0.f}};

  #pragma unroll 1
  for (int t = 0; t < 28; ++t) {
    const int cb = t & 1, pb = cb ^ 1;

    // ---- layer 1 (both M-tiles) ----
    float4 xa0 = *(const float4*)(xrow0 + t * 28);
    float4 xa1 = *(const float4*)(xrow1 + t * 28);
    float4 xb0 = float4{0.f, 0.f, 0.f, 0.f};
    float4 xb1 = float4{0.f, 0.f, 0.f, 0.f};
    if (g < 3) {
      xb0 = *(const float4*)(xrow0 + t * 28 + 4);
      xb1 = *(const float4*)(xrow1 + t * 28 + 4);
    }

    f32x4 acc1[2][2];
    #pragma unroll
    for (int m = 0; m < 2; ++m) {
      acc1[m][0] = f32x4{b1v[0], b1v[0], b1v[0], b1v[0]};
      acc1[m][1] = f32x4{b1v[1], b1v[1], b1v[1], b1v[1]};
    }

    if (t > 0) {
      #pragma unroll
      for (int kt = 0; kt < 4; ++kt) {
        const int k0 = (kt * 32 + g * 8) ^ swr;
        frag_t a0 = *(const frag_t*)&h1s[pb][li][k0];
        frag_t a1 = *(const frag_t*)&h1s[pb][16 + li][k0];
        acc1[0][0] = MFMA(a0, wB1[kt][0], acc1[0][0]);
        acc1[0][1] = MFMA(a0, wB1[kt][1], acc1[0][1]);
        acc1[1][0] = MFMA(a1, wB1[kt][0], acc1[1][0]);
        acc1[1][1] = MFMA(a1, wB1[kt][1], acc1[1][1]);
      }
    }
    {
      frag_t xA0 = packx(xa0, xb0);
      frag_t xA1 = packx(xa1, xb1);
      acc1[0][0] = MFMA(xA0, wBi1[0], acc1[0][0]);
      acc1[0][1] = MFMA(xA0, wBi1[1], acc1[0][1]);
      acc1[1][0] = MFMA(xA1, wBi1[0], acc1[1][0]);
      acc1[1][1] = MFMA(xA1, wBi1[1], acc1[1][1]);
    }

    #pragma unroll
    for (int m = 0; m < 2; ++m)
      #pragma unroll
      for (int nt = 0; nt < 2; ++nt) {
        const int colsw = ((wn * 32 + nt * 16) ^ swv) + li;
        #pragma unroll
        for (int r = 0; r < 4; ++r)
          h1s[cb][m * 16 + g * 4 + r][colsw] = f2bf_n(tanh_fast(acc1[m][nt][r]));
      }

    __syncthreads();   // B1: h1(t) visible

    // ---- layer 2 (both M-tiles) ----
    f32x4 acc2[2];
    acc2[0] = f32x4{b2v, b2v, b2v, b2v};
    acc2[1] = f32x4{b2v, b2v, b2v, b2v};
    #pragma unroll
    for (int kt = 0; kt < 4; ++kt) {
      const int k0 = (kt * 32 + g * 8) ^ swr;
      frag_t a0 = *(const frag_t*)&h1s[cb][li][k0];
      frag_t a1 = *(const frag_t*)&h1s[cb][16 + li][k0];
      acc2[0] = MFMA(a0, wBi2[kt], acc2[0]);
      acc2[1] = MFMA(a1, wBi2[kt], acc2[1]);
    }
    if (t > 0) {
      #pragma unroll
      for (int kt = 0; kt < 2; ++kt) {
        const int k0 = (kt * 32 + g * 8) ^ swr;
        frag_t a0 = *(const frag_t*)&h2s[pb][li][k0];
        frag_t a1 = *(const frag_t*)&h2s[pb][16 + li][k0];
        acc2[0] = MFMA(a0, wB2[kt], acc2[0]);
        acc2[1] = MFMA(a1, wB2[kt], acc2[1]);
      }
    }
    #pragma unroll
    for (int m = 0; m < 2; ++m) {
      const int colsw = ((wn * 16) ^ swv) + li;
      #pragma unroll
      for (int r = 0; r < 4; ++r)
        h2s[cb][m * 16 + g * 4 + r][colsw] = f2bf_n(tanh_fast(acc2[m][r]));
    }

    __syncthreads();   // B2: h2(t) visible

    // ---- FC accumulation (waves 0,1 split K=64; both M-tiles) ----
    if (wn < 2) {
      const int k0 = (wn * 32 + g * 8) ^ swr;
      frag_t bfc = *(const frag_t*)(wfp + t * 64);
      frag_t a0 = *(const frag_t*)&h2s[cb][li][k0];
      frag_t a1 = *(const frag_t*)&h2s[cb][16 + li][k0];
      fca[0] = MFMA(a0, bfc, fca[0]);
      fca[1] = MFMA(a1, bfc, fca[1]);
    }
  }

  // ---- epilogue: 2-way K-reduce + bias + store (strided: 320 > NTHR) ----
  if (wn < 2) {
    #pragma unroll
    for (int m = 0; m < 2; ++m)
      #pragma unroll
      for (int r = 0; r < 4; ++r)
        red[wn][m * 16 + g * 4 + r][li] = fca[m][r];
  }
  __syncthreads();
  for (int idx = tid; idx < 320; idx += NTHR) {
    const int b = idx / 10, c = idx - b * 10;
    out[(size_t)(blk * 32 + b) * 10 + c] = red[0][b][c] + red[1][b][c] + b_fc[c];
  }
}

extern "C" void kernel_launch(void* const* d_in, const int* in_sizes, int n_in,
                              void* d_out, int out_size, void* d_ws, size_t ws_size,
                              hipStream_t stream) {
  const float* x     = (const float*)d_in[0];
  const float* W_ih1 = (const float*)d_in[1];
  const float* W_hh1 = (const float*)d_in[2];
  const float* b_ih1 = (const float*)d_in[3];
  const float* b_hh1 = (const float*)d_in[4];
  const float* W_ih2 = (const float*)d_in[5];
  const float* W_hh2 = (const float*)d_in[6];
  const float* b_ih2 = (const float*)d_in[7];
  const float* b_hh2 = (const float*)d_in[8];
  const float* W_fc  = (const float*)d_in[9];
  const float* b_fc  = (const float*)d_in[10];
  unsigned short* ws = (unsigned short*)d_ws;

  cvt_weights<<<(WS_U16 + 255) / 256, 256, 0, stream>>>(W_ih1, W_hh1, W_ih2, W_hh2, W_fc, ws);
  rnn_mfma8<<<NBLK, NTHR, 0, stream>>>(x, ws, b_ih1, b_hh1, b_ih2, b_hh2, b_fc,
                                       (float*)d_out);
}